// Round 2
// baseline (122.595 us; speedup 1.0000x reference)
//
#include <hip/hip_runtime.h>
#include <math.h>

// MedianPool 17x17 stride 1, zero-padded SAME. Input (1,4,256,256) fp32.
//
// Round 2: 8-lane-per-pixel register-resident rank selection.
//  - octet of lanes holds the 289-value window in VGPRs (37/lane, +INF pad).
//    r1 used 73/lane and the compiler spilled (VGPR_Count=48!); 37 fits.
//  - seed scan: c0=#(v<0), cz=#(v==0) -> exact zero shortcut (border padding
//    duplicates) + side selection.
//  - first probe from normal-density secant through (0, c0); then
//    regula-falsi on (144.5 - count) with alternating-bisection safeguard;
//    exponential expansion for unbounded side. Prior guides speed only --
//    correctness holds for any finite input.
//  - stop at <=2 in-bracket candidates (or degenerate bracket: at most one
//    representable value remains, so min==2nd-min and any rank is correct);
//    extract 2 smallest in-bracket, merge across octet via shfl.
// Predicted: ~1.8e9 lane-ops, VALU-bound, ~30 us.

#define RAD 8
#define TW 8
#define TH 4
#define PW (TW + 2 * RAD)   // 24
#define PH (TH + 2 * RAD)   // 20
#define LDSW 25             // padded LDS stride
#define MEDRANK 144         // 0-based rank of lower median (of 289)

__global__ __launch_bounds__(256, 4)
void median17_kernel(const float* __restrict__ x, float* __restrict__ out) {
    __shared__ float tile[PH * LDSW];

    const int tid = threadIdx.x;
    const int bid = blockIdx.x;
    // grid: 4 ch * 64 y-tiles * 32 x-tiles = 8192 blocks, 32 pixels/block
    const int c  = bid >> 11;
    const int t  = bid & 2047;
    const int oy = (t >> 5) * TH;
    const int ox = (t & 31) * TW;
    const float* xc = x + c * 65536;

    // stage 20x24 patch, zero padded
    for (int i = tid; i < PH * PW; i += 256) {
        int r   = i / PW;
        int col = i - r * PW;
        int gy  = oy - RAD + r;
        int gx  = ox - RAD + col;
        float v = 0.0f;
        if ((unsigned)gy < 256u && (unsigned)gx < 256u) v = xc[gy * 256 + gx];
        tile[r * LDSW + col] = v;
    }
    __syncthreads();

    const int j  = tid & 7;     // lane within octet (one pixel per 8 lanes)
    const int g  = tid >> 3;    // pixel 0..31
    const int py = g >> 3;
    const int px = g & 7;

    const float FINF = __builtin_inff();

    // lane j owns flat window indices [37j, 37j+37); f>=289 padded +INF.
    // flat f -> (dy,dx) = (f/17, f%17).
    float w[37];
    {
        const int f0  = 37 * j;
        const int dy0 = f0 / 17;
        int dx = f0 - dy0 * 17;
        int a  = (py + dy0) * LDSW + px + dx;
#pragma unroll
        for (int k = 0; k < 37; ++k) {
            bool ok   = (k < 30) || (j < 7);     // f0+k < 289
            float v   = tile[ok ? a : 0];
            w[k]      = ok ? v : FINF;
            bool wrap = (dx == 16);
            a  += wrap ? (LDSW - 16) : 1;
            dx  = wrap ? 0 : dx + 1;
        }
    }

    // seed counters: c0 = #(v<0), cz = #(v==0), packed reduce over octet
    int cn = 0, ce = 0;
#pragma unroll
    for (int k = 0; k < 37; ++k) {
        cn += (w[k] < 0.0f) ? 1 : 0;
        ce += (w[k] == 0.0f) ? 1 : 0;
    }
    int pk = cn | (ce << 16);
    pk += __shfl_xor(pk, 1);
    pk += __shfl_xor(pk, 2);
    pk += __shfl_xor(pk, 4);
    const int c0 = pk & 0xffff;
    const int cz = pk >> 16;

    float med;
    if (c0 <= MEDRANK && MEDRANK < c0 + cz) {
        // zero is the exact lower median (border pixels with padding dups)
        med = 0.0f;
    } else {
        float lo, hi; int lc, hc;
        if (c0 > MEDRANK) { lo = -FINF; lc = 0;  hi = 0.0f; hc = c0;  }
        else              { lo = 0.0f;  lc = c0; hi = FINF; hc = 289; }

        for (int it = 0; it < 100; ++it) {
            if (hc - lc <= 2) break;
            float mid;
            if (it == 0) {
                // density-guided secant through (0, c0); sign matches side
                mid = 2.5066283f * (0.5f - (float)c0 * (1.0f / 289.0f));
            } else if (hi == FINF) {            // lo > 0 measured; expand up
                mid = fminf(2.0f * lo, 3.0e38f);
            } else if (lo == -FINF) {           // hi < 0 measured; expand down
                mid = fmaxf(2.0f * hi, -3.0e38f);
            } else if (it & 1) {                // safeguarded bisection
                mid = 0.5f * (lo + hi);
            } else {                            // regula falsi on counts
                float wd   = hi - lo;
                float frac = (float)(144 - lc) + 0.5f;
                mid = lo + wd * (frac / (float)(hc - lc));
                mid = fminf(fmaxf(mid, lo + 0.03125f * wd), hi - 0.03125f * wd);
            }
            if (!(mid > lo && mid < hi)) break;   // degenerate bracket

            int q = 0;
#pragma unroll
            for (int k = 0; k < 37; ++k) q += (w[k] < mid) ? 1 : 0;
            q += __shfl_xor(q, 1);
            q += __shfl_xor(q, 2);
            q += __shfl_xor(q, 4);

            if (q <= MEDRANK) { lo = mid; lc = q; }
            else              { hi = mid; hc = q; }
        }

        // extract rank rk (0 or 1) among values in [lo, hi).
        // degenerate-break case: only one representable value in [lo,hi),
        // so s0 == s1 and either pick is exact.
        const int rk = MEDRANK - lc;
        float q0a = FINF, q1a = FINF, q0b = FINF, q1b = FINF;
#pragma unroll
        for (int k = 0; k < 37; k += 2) {
            {
                float v  = w[k];
                bool in  = (v >= lo) & (v < hi);
                float xv = in ? v : FINF;
                float t0 = fminf(q0a, xv);
                q1a = fminf(q1a, fmaxf(q0a, xv));
                q0a = t0;
            }
            if (k + 1 < 37) {
                float v  = w[k + 1];
                bool in  = (v >= lo) & (v < hi);
                float xv = in ? v : FINF;
                float t0 = fminf(q0b, xv);
                q1b = fminf(q1b, fmaxf(q0b, xv));
                q0b = t0;
            }
        }
        float s0 = fminf(q0a, q0b);
        float s1 = fminf(fminf(q1a, q1b), fmaxf(q0a, q0b));
#pragma unroll
        for (int d = 1; d <= 4; d <<= 1) {
            float r0 = __shfl_xor(s0, d);
            float r1 = __shfl_xor(s1, d);
            float n0 = fminf(s0, r0);
            float n1 = fminf(fminf(s1, r1), fmaxf(s0, r0));
            s0 = n0; s1 = n1;
        }
        med = (rk == 0) ? s0 : s1;
    }

    if (j == 0) {
        out[c * 65536 + (oy + py) * 256 + ox + px] = med;
    }
}

extern "C" void kernel_launch(void* const* d_in, const int* in_sizes, int n_in,
                              void* d_out, int out_size, void* d_ws, size_t ws_size,
                              hipStream_t stream) {
    const float* x = (const float*)d_in[0];
    float* out = (float*)d_out;
    median17_kernel<<<dim3(8192), dim3(256), 0, stream>>>(x, out);
}

// Round 6
// 122.489 us; speedup vs baseline: 1.0009x; 1.0009x over previous
//
#include <hip/hip_runtime.h>
#include <math.h>

// MedianPool 17x17 stride 1, zero-padded SAME. Input (1,4,256,256) fp32.
//
// Round 3 kernel, third resubmit (r3/r4/r5 benches all GPUAcquisitionTimeout
// -- kernel never executed; preserving the clean A/B vs r2's measurement):
//   r2 structure + FORCED register residency of the window.
//   r2 post-mortem: VGPR_Count=28 proved the compiler rematerialized w[]
//   from LDS on every bisection scan (3 VALU + 1 ds_read per element per
//   scan instead of 2 VALU). Fix: asm-pin each w[k] after the load --
//   the empty asm "redefines" the value, so LDS remat becomes illegal and
//   the 37 window values must live in VGPRs across the whole selection.
//   Everything else is byte-identical to the r2 kernel (passed, absmax 0).
// Predicted: VGPR ~64-90, dur 77.6 -> 32-45 us, bank conflicts < 0.8M.

#define RAD 8
#define TW 8
#define TH 4
#define PW (TW + 2 * RAD)   // 24
#define PH (TH + 2 * RAD)   // 20
#define LDSW 25             // padded LDS stride
#define MEDRANK 144         // 0-based rank of lower median (of 289)

__global__ __launch_bounds__(256, 4)
void median17_kernel(const float* __restrict__ x, float* __restrict__ out) {
    __shared__ float tile[PH * LDSW];

    const int tid = threadIdx.x;
    const int bid = blockIdx.x;
    // grid: 4 ch * 64 y-tiles * 32 x-tiles = 8192 blocks, 32 pixels/block
    const int c  = bid >> 11;
    const int t  = bid & 2047;
    const int oy = (t >> 5) * TH;
    const int ox = (t & 31) * TW;
    const float* xc = x + c * 65536;

    // stage 20x24 patch, zero padded
    for (int i = tid; i < PH * PW; i += 256) {
        int r   = i / PW;
        int col = i - r * PW;
        int gy  = oy - RAD + r;
        int gx  = ox - RAD + col;
        float v = 0.0f;
        if ((unsigned)gy < 256u && (unsigned)gx < 256u) v = xc[gy * 256 + gx];
        tile[r * LDSW + col] = v;
    }
    __syncthreads();

    const int j  = tid & 7;     // lane within octet (one pixel per 8 lanes)
    const int g  = tid >> 3;    // pixel 0..31
    const int py = g >> 3;
    const int px = g & 7;

    const float FINF = __builtin_inff();

    // lane j owns flat window indices [37j, 37j+37); f>=289 padded +INF.
    // flat f -> (dy,dx) = (f/17, f%17).
    float w[37];
    {
        const int f0  = 37 * j;
        const int dy0 = f0 / 17;
        int dx = f0 - dy0 * 17;
        int a  = (py + dy0) * LDSW + px + dx;
#pragma unroll
        for (int k = 0; k < 37; ++k) {
            bool ok   = (k < 30) || (j < 7);     // f0+k < 289
            float v   = tile[ok ? a : 0];
            w[k]      = ok ? v : FINF;
            bool wrap = (dx == 16);
            a  += wrap ? (LDSW - 16) : 1;
            dx  = wrap ? 0 : dx + 1;
        }
    }

    // Pin the window into VGPRs: the empty asm "writes" each w[k], so the
    // compiler cannot rematerialize it from LDS in the scan loops below.
#pragma unroll
    for (int k = 0; k < 37; ++k) {
        asm volatile("" : "+v"(w[k]));
    }

    // seed counters: c0 = #(v<0), cz = #(v==0), packed reduce over octet
    int cn = 0, ce = 0;
#pragma unroll
    for (int k = 0; k < 37; ++k) {
        cn += (w[k] < 0.0f) ? 1 : 0;
        ce += (w[k] == 0.0f) ? 1 : 0;
    }
    int pk = cn | (ce << 16);
    pk += __shfl_xor(pk, 1);
    pk += __shfl_xor(pk, 2);
    pk += __shfl_xor(pk, 4);
    const int c0 = pk & 0xffff;
    const int cz = pk >> 16;

    float med;
    if (c0 <= MEDRANK && MEDRANK < c0 + cz) {
        // zero is the exact lower median (border pixels with padding dups)
        med = 0.0f;
    } else {
        float lo, hi; int lc, hc;
        if (c0 > MEDRANK) { lo = -FINF; lc = 0;  hi = 0.0f; hc = c0;  }
        else              { lo = 0.0f;  lc = c0; hi = FINF; hc = 289; }

        for (int it = 0; it < 100; ++it) {
            if (hc - lc <= 2) break;
            float mid;
            if (it == 0) {
                // density-guided secant through (0, c0); sign matches side
                mid = 2.5066283f * (0.5f - (float)c0 * (1.0f / 289.0f));
            } else if (hi == FINF) {            // lo > 0 measured; expand up
                mid = fminf(2.0f * lo, 3.0e38f);
            } else if (lo == -FINF) {           // hi < 0 measured; expand down
                mid = fmaxf(2.0f * hi, -3.0e38f);
            } else if (it & 1) {                // safeguarded bisection
                mid = 0.5f * (lo + hi);
            } else {                            // regula falsi on counts
                float wd   = hi - lo;
                float frac = (float)(144 - lc) + 0.5f;
                mid = lo + wd * (frac / (float)(hc - lc));
                mid = fminf(fmaxf(mid, lo + 0.03125f * wd), hi - 0.03125f * wd);
            }
            if (!(mid > lo && mid < hi)) break;   // degenerate bracket

            int q = 0;
#pragma unroll
            for (int k = 0; k < 37; ++k) q += (w[k] < mid) ? 1 : 0;
            q += __shfl_xor(q, 1);
            q += __shfl_xor(q, 2);
            q += __shfl_xor(q, 4);

            if (q <= MEDRANK) { lo = mid; lc = q; }
            else              { hi = mid; hc = q; }
        }

        // extract rank rk (0 or 1) among values in [lo, hi).
        // degenerate-break case: only one representable value in [lo,hi),
        // so s0 == s1 and either pick is exact.
        const int rk = MEDRANK - lc;
        float q0a = FINF, q1a = FINF, q0b = FINF, q1b = FINF;
#pragma unroll
        for (int k = 0; k < 37; k += 2) {
            {
                float v  = w[k];
                bool in  = (v >= lo) & (v < hi);
                float xv = in ? v : FINF;
                float t0 = fminf(q0a, xv);
                q1a = fminf(q1a, fmaxf(q0a, xv));
                q0a = t0;
            }
            if (k + 1 < 37) {
                float v  = w[k + 1];
                bool in  = (v >= lo) & (v < hi);
                float xv = in ? v : FINF;
                float t0 = fminf(q0b, xv);
                q1b = fminf(q1b, fmaxf(q0b, xv));
                q0b = t0;
            }
        }
        float s0 = fminf(q0a, q0b);
        float s1 = fminf(fminf(q1a, q1b), fmaxf(q0a, q0b));
#pragma unroll
        for (int d = 1; d <= 4; d <<= 1) {
            float r0 = __shfl_xor(s0, d);
            float r1 = __shfl_xor(s1, d);
            float n0 = fminf(s0, r0);
            float n1 = fminf(fminf(s1, r1), fmaxf(s0, r0));
            s0 = n0; s1 = n1;
        }
        med = (rk == 0) ? s0 : s1;
    }

    if (j == 0) {
        out[c * 65536 + (oy + py) * 256 + ox + px] = med;
    }
}

extern "C" void kernel_launch(void* const* d_in, const int* in_sizes, int n_in,
                              void* d_out, int out_size, void* d_ws, size_t ws_size,
                              hipStream_t stream) {
    const float* x = (const float*)d_in[0];
    float* out = (float*)d_out;
    median17_kernel<<<dim3(8192), dim3(256), 0, stream>>>(x, out);
}